// Round 6
// baseline (193.687 us; speedup 1.0000x reference)
//
#include <hip/hip_runtime.h>
#include <hip/hip_bf16.h>
#include <stdint.h>

// ===================================================================
// PriorLayer online BP scan, round 8. s_t = norm(diag(p_t) T s_{t-1}).
// R1-R7 verdict: per-epoch cost pinned 4700-5700 cyc under EVERY body
// change (conflicts fixed 5x in R7 -> zero time delta). Accounting:
// MFMA 620 + LDS 770 + VALU 1100 cyc/epoch, rest = exposed latency of
// the 8-wave all-to-all barrier convoy (R3: 2 blocks/CU serialize
// perfectly => waves never fill each other's stalls).
// R8: WAVE-AUTONOMOUS SCAN — no inter-wave deps, NO barriers in scan:
//  - Each wave computes the full 256-dim matvec for its own 16 chunks:
//    16 row-tiles x 8 kb = 128 MFMAs/epoch; T read from LDS (staged
//    once, fragment-major bf16, 128KB, shared read-only by 2 waves).
//  - State = wave-private 8KB LDS scratch; chain is ds_write ->
//    lgkmcnt -> ds_read -> MFMA, latency hidden by 16 independent
//    row-tile chains (ILP), not by other waves.
//  - 2 independent waves/block, 256 blocks (144KB LDS => 1 block/CU),
//    CLEN=8, BURN=6 => 14 serial epochs (vs 22).
//  - Z/entropy: lane-sum + 2 shfl_xor (quads) in-epoch, off-chain by
//    dataflow (nothing downstream depends on stores).
//  - A/B fragment maps + C->B write scatter lifted VERBATIM from
//    R7 (harness-verified).
// ===================================================================

#define DIM   256
#define SEQ   65536
#define G     16                        // chunks per wave
#define WPB   2                         // waves per block
#define CLEN  8                         // outputs per chunk
#define NBLK  (SEQ / (G * WPB * CLEN))  // 256 blocks -> 1 per CU
#define BURN  6
#define STEPS (BURN + CLEN)             // 14 epochs
#define TPB   (WPB * 64)                // 128

#define TA_SHORTS (16 * 8 * 64 * 8)     // T fragments: 65536 shorts = 128KB
#define SB_SHORTS (8 * 64 * 8)          // state: 4096 shorts = 8KB / wave
#define LDS_BYTES ((TA_SHORTS + WPB * SB_SHORTS) * 2)   // 147456

typedef short bf16x8 __attribute__((ext_vector_type(8)));
typedef float f32x4  __attribute__((ext_vector_type(4)));

static __device__ __forceinline__ unsigned short f2bf(float x) {
  __hip_bfloat16 h = __float2bfloat16(x);
  return *reinterpret_cast<unsigned short*>(&h);
}

__global__ __launch_bounds__(TPB, 1)
void prior_scan_kernel(const float* __restrict__ probs,
                       const float* __restrict__ tp,
                       float* __restrict__ out) {
  extern __shared__ short lds[];
  short* TA = lds;                      // [rt][kb][qd*16+m][j] bf16 of T
  const int tid  = threadIdx.x;
  const int w    = tid >> 6;
  const int lane = tid & 63;
  const int n    = lane & 15;           // chunk-within-wave = MFMA col
  const int quad = lane >> 4;
  short* SB = lds + TA_SHORTS + w * SB_SHORTS;   // this wave's state

  // ---- stage T into fragment-major bf16 (coalesced read, b64 scatter)
  //      element (r,c): rt=r>>4, m=r&15, kb=c>>5, qd=(c>>3)&3, j=c&7
  for (int s = tid * 4; s < DIM * DIM; s += TPB * 4) {
    const int r = s >> 8, c = s & 255;
    const int rt = r >> 4, m = r & 15;
    const int kb = c >> 5, qd = (c >> 3) & 3, j0 = c & 7;  // j0 in {0,4}
    f32x4 f = *reinterpret_cast<const f32x4*>(tp + s);
    ushort4 v;
    v.x = f2bf(f[0]); v.y = f2bf(f[1]); v.z = f2bf(f[2]); v.w = f2bf(f[3]);
    *reinterpret_cast<ushort4*>(TA + ((rt * 8 + kb) * 64 + qd * 16 + m) * 8 + j0) = v;
  }

  // ---- init own state = uniform 1/256 (bf16-exact; scale-invariant)
  {
    ushort4 u; u.x = u.y = u.z = u.w = (unsigned short)0x3B80;
    ushort4* p = reinterpret_cast<ushort4*>(SB);
    for (int i = lane; i < SB_SHORTS / 4; i += 64) p[i] = u;
  }
  __syncthreads();                      // the ONLY barrier (TA visibility)

  const int g = (blockIdx.x * WPB + w) * G + n;   // this lane's chunk id

  // ---- one epoch: full 256-dim matvec for this wave's 16 chunks
  //      (MAIN=false: burn — no partials/outputs/qp)
  auto epoch = [&](int e, bool MAIN) {
    const int t  = g * CLEN - BURN + e;
    const int tc = t < 0 ? 0 : t;       // clamped (value unused when t<0)

    // B fragments: linear conflict-free b128 (R7-verified layout)
    bf16x8 B[8];
#pragma unroll
    for (int kb = 0; kb < 8; kb++)
      B[kb] = *reinterpret_cast<const bf16x8*>(SB + kb * 512 + lane * 8);

    // observation rows for this epoch (consumed after MFMAs: ~2.5k cyc slack)
    f32x4 P[16];
#pragma unroll
    for (int rt = 0; rt < 16; rt++)
      P[rt] = *reinterpret_cast<const f32x4*>(
          probs + (size_t)tc * DIM + rt * 16 + quad * 4);

    // C = T @ u : 16 independent row-tile chains, dep distance 16
    f32x4 C[16];
#pragma unroll
    for (int rt = 0; rt < 16; rt++) C[rt] = f32x4{0.f, 0.f, 0.f, 0.f};
#pragma unroll
    for (int kb = 0; kb < 8; kb++) {
      const short* ta = TA + kb * 512 + lane * 8;
#pragma unroll
      for (int rt = 0; rt < 16; rt++) {
        bf16x8 a = *reinterpret_cast<const bf16x8*>(ta + rt * 4096);
        C[rt] = __builtin_amdgcn_mfma_f32_16x16x32_bf16(a, B[kb], C[rt], 0, 0, 0);
      }
    }

    // q = C .* p   (C/D: row = rt*16 + quad*4 + v, col = n)
#pragma unroll
    for (int rt = 0; rt < 16; rt++)
#pragma unroll
      for (int v = 0; v < 4; v++)
        C[rt][v] *= P[rt][v];

    // write next state (2^-6 rescale; uniform pre-start), R7-verified map:
    //   row r=RT*16+quad*4+v -> kb=RT>>1, quad'=(RT&1)*2+(quad>>1), j=(quad&1)*4+v
#pragma unroll
    for (int RT = 0; RT < 16; RT++) {
      ushort4 sp;
      if (t < 0) {
        sp.x = sp.y = sp.z = sp.w = (unsigned short)0x3B80;
      } else {
        sp.x = f2bf(C[RT][0] * 0.015625f);
        sp.y = f2bf(C[RT][1] * 0.015625f);
        sp.z = f2bf(C[RT][2] * 0.015625f);
        sp.w = f2bf(C[RT][3] * 0.015625f);
      }
      *reinterpret_cast<ushort4*>(
          SB + (RT >> 1) * 512 +
          ((((RT & 1) * 2 + (quad >> 1)) * 16) + n) * 8 + (quad & 1) * 4) = sp;
    }

    if (MAIN) {
      // Z / entropy: lane-private sum + 2 shfl_xor over quads; all
      // downstream (stores) is off the serial chain by dataflow.
      float sz = 0.f, sl = 0.f;
#pragma unroll
      for (int rt = 0; rt < 16; rt++)
#pragma unroll
        for (int v = 0; v < 4; v++) {
          float qq = C[rt][v];
          sz += qq;
          sl += qq * __logf(qq + 1e-30f);
        }
      sz += __shfl_xor(sz, 16); sz += __shfl_xor(sz, 32);
      sl += __shfl_xor(sl, 16); sl += __shfl_xor(sl, 32);
      const float zi = __builtin_amdgcn_rcpf(sz);
#pragma unroll
      for (int rt = 0; rt < 16; rt++) {
        f32x4 o;
#pragma unroll
        for (int v = 0; v < 4; v++) o[v] = C[rt][v] * zi;
        *reinterpret_cast<f32x4*>(
            out + (size_t)t * DIM + rt * 16 + quad * 4) = o;
      }
      if (quad == 0)                    // one lane per chunk (n == lane)
        out[(size_t)SEQ * DIM + t] = __logf(sz) - sl * zi;
    }
  };

  for (int e = 0; e < BURN; e++)  epoch(e, false);
  for (int e = BURN; e < STEPS; e++) epoch(e, true);
}

extern "C" void kernel_launch(void* const* d_in, const int* in_sizes, int n_in,
                              void* d_out, int out_size, void* d_ws, size_t ws_size,
                              hipStream_t stream) {
  const float* probs = (const float*)d_in[0];   // (65536, 256)
  const float* tp    = (const float*)d_in[1];   // (256, 256)
  float* out         = (float*)d_out;           // 65536*256 probs + 65536 H

  static bool configured = false;
  if (!configured) {
    hipFuncSetAttribute(reinterpret_cast<const void*>(prior_scan_kernel),
                        hipFuncAttributeMaxDynamicSharedMemorySize, LDS_BYTES);
    configured = true;
  }

  hipLaunchKernelGGL(prior_scan_kernel, dim3(NBLK), dim3(TPB), LDS_BYTES,
                     stream, probs, tp, out);
}

// Round 7
// 135.459 us; speedup vs baseline: 1.4299x; 1.4299x over previous
//
#include <hip/hip_runtime.h>
#include <hip/hip_bf16.h>
#include <stdint.h>

// ===================================================================
// PriorLayer online BP scan, round 9. s_t = norm(diag(p_t) T s_{t-1}).
// R8 post-mortem: wave-autonomous failed because A stayed in LDS
// (VGPR=144 -> per-MFMA ds_read+wait, 20k cyc/epoch). R1-R7: 8-wave
// barrier epoch pinned ~4700-5700 cyc regardless of body; conflicts
// irrelevant (R7). R9: shrink the barrier group and keep T RESIDENT:
//  - 4 waves x 64 rows of T in registers (A[4][8]=128 VGPR, the R4-
//    proven footprint), one shared 16-chunk scan, CLEN=16, 256 blocks.
//  - Per epoch/wave: 8 conflict-free b128 B-reads (into regs ONCE),
//    32 MFMAs from regs, 4 b64 state writes, one 4-wave barrier.
//    vs R6: barrier group 8->4, LDS reads 64->32, issue fills latency.
//  - Fragment-major state SB[kb][lane][j] (R7-verified); write map
//    r=w*64+rt*16+quad*4+v -> kb=w*2+(rt>>1), qd=(rt&1)*2+(quad>>1),
//    j=(quad&1)*4+v (same formula, rt extended to 0..3).
//  - Lane-private partials pZL[par][n][w*4+quad] (no shuffles);
//    finalize deferred one epoch (R6 skeleton verbatim).
//  - cur/nxt compile-time via paired calls (rule-#20 safe).
//  - __launch_bounds__(256,1): ~290 regs, 1 wave/SIMD, no spill.
// ===================================================================

#define DIM   256
#define SEQ   65536
#define G     16                    // chunks per block (MFMA cols)
#define CLEN  16                    // outputs per chunk
#define NBLK  (SEQ / (G * CLEN))    // 256 blocks -> 1 per CU
#define BURN  6
#define STEPS (BURN + CLEN)         // 22 (even — pairing relies on it)
#define NW    4
#define TPB   (NW * 64)             // 256
#define PGP   17                    // pZL padded row (f32x2)

typedef short bf16x8 __attribute__((ext_vector_type(8)));
typedef float f32x4  __attribute__((ext_vector_type(4)));
typedef float f32x2  __attribute__((ext_vector_type(2)));

static __device__ __forceinline__ unsigned short f2bf(float x) {
  __hip_bfloat16 h = __float2bfloat16(x);
  return *reinterpret_cast<unsigned short*>(&h);
}

// LDS-only barrier: do NOT drain vmcnt (global stores / prefetch loads
// stay in flight). lgkmcnt(0) orders all ds ops.
static __device__ __forceinline__ void lds_barrier() {
  asm volatile("s_waitcnt lgkmcnt(0)" ::: "memory");
  __builtin_amdgcn_s_barrier();
}

__global__ __launch_bounds__(TPB, 1)
void prior_scan_kernel(const float* __restrict__ probs,
                       const float* __restrict__ tp,
                       float* __restrict__ out) {
  // SB: double-buffered state, fragment-major SB[buf][kb][lane][j]
  //     (reads linear/conflict-free; writes scatter ~linear).
  // pZL: parity-buffered lane partials [par][n][g=w*4+quad].
  __shared__ __attribute__((aligned(16))) short SB[2][8][64][8];
  __shared__ __attribute__((aligned(16))) f32x2 pZL[2][G][PGP];

  const int tid  = threadIdx.x;
  const int w    = tid >> 6;
  const int lane = tid & 63;
  const int n    = lane & 15;       // chunk within block = MFMA col
  const int quad = lane >> 4;
  const int g    = blockIdx.x * G + n;   // global chunk id (per lane)

  // ---- T rows w*64..w*64+63 into A-fragments (128 VGPR, resident)
  //      A[rt][kb]: m=lane&15 -> row w*64+rt*16+m; k=quad*8+j
  bf16x8 A[4][8];
#pragma unroll
  for (int rt = 0; rt < 4; rt++) {
    const int row = w * 64 + rt * 16 + n;
#pragma unroll
    for (int kb = 0; kb < 8; kb++) {
      const float* p = tp + row * DIM + kb * 32 + quad * 8;
      f32x4 f0 = *reinterpret_cast<const f32x4*>(p);
      f32x4 f1 = *reinterpret_cast<const f32x4*>(p + 4);
      bf16x8 a;
#pragma unroll
      for (int j = 0; j < 4; j++) {
        a[j]     = (short)f2bf(f0[j]);
        a[4 + j] = (short)f2bf(f1[j]);
      }
      A[rt][kb] = a;
    }
  }

  // ---- init state buf 0 = uniform 1/256 (bf16-exact; scale-invariant)
  {
    ushort4 u; u.x = u.y = u.z = u.w = (unsigned short)0x3B80;
    ushort4* dst = reinterpret_cast<ushort4*>(&SB[0][0][0][0]) + tid * 4;
    dst[0] = u; dst[1] = u; dst[2] = u; dst[3] = u;   // 4096 shorts total
  }

  // ---- observation fragment loader (lane-owned, direct from global)
  auto loadp = [&](int s, int rt, bool clamp) -> f32x4 {
    int t = g * CLEN - BURN + s;
    if (clamp && t < 0) t = 0;      // value unused when t<0
    return *reinterpret_cast<const f32x4*>(
        probs + (size_t)t * DIM + w * 64 + rt * 16 + quad * 4);
  };

  // 2-deep register prefetch ring
  f32x4 pf[2][4];
#pragma unroll
  for (int rt = 0; rt < 4; rt++) {
    pf[0][rt] = loadp(0, rt, true);
    pf[1][rt] = loadp(1, rt, true);
  }

  __syncthreads();                  // A/pf are private; orders SB init

  float qp[4][4];                   // q of previous epoch (deferred norm)

  // --- full 256-dim matvec, this wave's 64 rows: q = (T @ u) .* p
  auto matvec = [&](int cur, float (&q)[4][4]) {
    bf16x8 B[8];
#pragma unroll
    for (int kb = 0; kb < 8; kb++)  // linear conflict-free b128
      B[kb] = *reinterpret_cast<const bf16x8*>(&SB[cur][kb][lane][0]);
    f32x4 aE[4], aO[4];
#pragma unroll
    for (int rt = 0; rt < 4; rt++) {
      aE[rt] = f32x4{0.f, 0.f, 0.f, 0.f};
      aO[rt] = f32x4{0.f, 0.f, 0.f, 0.f};
    }
#pragma unroll
    for (int kb = 0; kb < 8; kb += 2) {
#pragma unroll
      for (int rt = 0; rt < 4; rt++) {
        aE[rt] = __builtin_amdgcn_mfma_f32_16x16x32_bf16(A[rt][kb],     B[kb],     aE[rt], 0, 0, 0);
        aO[rt] = __builtin_amdgcn_mfma_f32_16x16x32_bf16(A[rt][kb + 1], B[kb + 1], aO[rt], 0, 0, 0);
      }
    }
#pragma unroll
    for (int rt = 0; rt < 4; rt++)
#pragma unroll
      for (int v = 0; v < 4; v++)   // C/D: row=rt*16+quad*4+v, col=n
        q[rt][v] = (aE[rt][v] + aO[rt][v]) * pf[cur][rt][v];
  };

  // write map: r=w*64+rt*16+quad*4+v -> kb=w*2+(rt>>1),
  //            qd=(rt&1)*2+(quad>>1), j=(quad&1)*4+v  (R7-verified)
  auto write_state = [&](int nxt, const float (&q)[4][4]) {
#pragma unroll
    for (int rt = 0; rt < 4; rt++) {
      ushort4 sp;
      sp.x = f2bf(q[rt][0] * 0.015625f);
      sp.y = f2bf(q[rt][1] * 0.015625f);
      sp.z = f2bf(q[rt][2] * 0.015625f);
      sp.w = f2bf(q[rt][3] * 0.015625f);
      *reinterpret_cast<ushort4*>(
          &SB[nxt][w * 2 + (rt >> 1)][((rt & 1) * 2 + (quad >> 1)) * 16 + n]
             [(quad & 1) * 4]) = sp;
    }
  };

  // --- deferred finalize of epoch e1 (partials in pZL[pbuf])
  auto finalize = [&](int pbuf, int e1) {
    float Z = 0.f, L = 0.f;
#pragma unroll
    for (int j = 0; j < 8; j++) {   // 16 f32x2 partials for chunk n
      f32x4 r = *reinterpret_cast<const f32x4*>(&pZL[pbuf][n][j * 2]);
      Z += r[0] + r[2];
      L += r[1] + r[3];
    }
    const float zi = __builtin_amdgcn_rcpf(Z);
    const int t1 = g * CLEN + (e1 - BURN);
#pragma unroll
    for (int rt = 0; rt < 4; rt++) {
      f32x4 o;
#pragma unroll
      for (int v = 0; v < 4; v++) o[v] = qp[rt][v] * zi;
      *reinterpret_cast<f32x4*>(
          out + (size_t)t1 * DIM + w * 64 + rt * 16 + quad * 4) = o;
    }
    if (tid < 16)                   // n == tid for these lanes
      out[(size_t)SEQ * DIM + t1] = __logf(Z) - L * zi;
  };

  // --- burn epoch: NO partials, NO finalize, NO qp carry
  auto burn_body = [&](int e, int cur, int nxt) {
    float q[4][4];
    matvec(cur, q);
#pragma unroll
    for (int rt = 0; rt < 4; rt++)
      pf[cur][rt] = loadp(e + 2, rt, true);   // e+2 <= BURN+1 < STEPS
    const int t = g * CLEN - BURN + e;
    if (t < 0) {                    // pre-start: hold uniform state
      ushort4 sp;
      sp.x = sp.y = sp.z = sp.w = (unsigned short)0x3B80;
#pragma unroll
      for (int rt = 0; rt < 4; rt++)
        *reinterpret_cast<ushort4*>(
            &SB[nxt][w * 2 + (rt >> 1)][((rt & 1) * 2 + (quad >> 1)) * 16 + n]
               [(quad & 1) * 4]) = sp;
    } else {
      write_state(nxt, q);
    }
    lds_barrier();
  };

  // --- output epoch: lane-private partials + deferred finalize of e-1
  auto main_body = [&](int e, int cur, int nxt) {
    float q[4][4];
    matvec(cur, q);
    int ps = e + 2; if (ps > STEPS - 1) ps = STEPS - 1;
#pragma unroll
    for (int rt = 0; rt < 4; rt++)
      pf[cur][rt] = loadp(ps, rt, false);     // t >= 0 for all mains
    write_state(nxt, q);

    float sz = 0.f, sl = 0.f;       // lane-private over 16 rows
#pragma unroll
    for (int rt = 0; rt < 4; rt++)
#pragma unroll
      for (int v = 0; v < 4; v++) {
        float qq = q[rt][v];
        sz += qq;
        sl += qq * __logf(qq + 1e-30f);
      }
    pZL[cur][n][w * 4 + quad] = f32x2{sz, sl};

    if (e > BURN) finalize(nxt, e - 1);       // nxt == (e-1)&1

#pragma unroll
    for (int rt = 0; rt < 4; rt++)
#pragma unroll
      for (int v = 0; v < 4; v++) qp[rt][v] = q[rt][v];
    lds_barrier();
  };

  for (int e = 0; e < BURN; e += 2) {         // BURN even
    burn_body(e, 0, 1);
    burn_body(e + 1, 1, 0);
  }
  for (int e = BURN; e < STEPS; e += 2) {     // STEPS even, BURN even
    main_body(e, 0, 1);
    main_body(e + 1, 1, 0);
  }

  // --- tail: finalize epoch STEPS-1 (partials in pZL[(STEPS-1)&1])
  finalize((STEPS - 1) & 1, STEPS - 1);
}

extern "C" void kernel_launch(void* const* d_in, const int* in_sizes, int n_in,
                              void* d_out, int out_size, void* d_ws, size_t ws_size,
                              hipStream_t stream) {
  const float* probs = (const float*)d_in[0];   // (65536, 256)
  const float* tp    = (const float*)d_in[1];   // (256, 256)
  float* out         = (float*)d_out;           // 65536*256 probs + 65536 H

  hipLaunchKernelGGL(prior_scan_kernel, dim3(NBLK), dim3(TPB), 0, stream,
                     probs, tp, out);
}